// Round 2
// baseline (323.403 us; speedup 1.0000x reference)
//
#include <hip/hip_runtime.h>

typedef unsigned short u16;
typedef __attribute__((ext_vector_type(8))) short bf16x8;
typedef __attribute__((ext_vector_type(8))) unsigned short u16x8;
typedef __attribute__((ext_vector_type(4))) unsigned short u16x4;
typedef __attribute__((ext_vector_type(4))) float f32x4;

#define DEVI static __device__ __forceinline__

DEVI u16 f2b(float f) {
  unsigned u = __builtin_bit_cast(unsigned, f);
  return (u16)((u + 0x7FFFu + ((u >> 16) & 1u)) >> 16);
}

DEVI void gload_lds16(const void* g, void* l) {
  __builtin_amdgcn_global_load_lds(
      (const __attribute__((address_space(1))) unsigned int*)g,
      (__attribute__((address_space(3))) unsigned int*)l, 16, 0, 0);
}

#define LGKM0 asm volatile("s_waitcnt lgkmcnt(0)" ::: "memory")
#define VMW(N) asm volatile("s_waitcnt vmcnt(" #N ")" ::: "memory")
DEVI void sbar() {
  __builtin_amdgcn_sched_barrier(0);
  __builtin_amdgcn_s_barrier();
  __builtin_amdgcn_sched_barrier(0);
}
DEVI bf16x8 mfma_ld(const u16* p) { return *(const bf16x8*)p; }

// ---------------- weight image prep ----------------
// img: 32 pieces x 16384 u16 (32 KiB), piece p = h*4 + {q,k,v,o}, pre-swizzled
// "LDS image": 16B chunk index XOR'd with (row&7) so fused kernel stages linearly.
// q/k/v pieces: 64 rows (out-dim within head) x 256 k.  Wq scaled by 0.125.
// o piece: 256 rows (out channel c) x 64 k (dd within head).
// bqv[512] = bq*0.125 ; bo2[256] = bo + bv @ Wo  (bv folded; bk dropped:
// (q+bq)·(k+bk) = (q+bq)·k + rowconst -> softmax-invariant).
__global__ __launch_bounds__(256) void prep_w2(
    const float* __restrict__ Wq, const float* __restrict__ Wk,
    const float* __restrict__ Wv, const float* __restrict__ Wo,
    const float* __restrict__ bq, const float* __restrict__ bv,
    const float* __restrict__ bo, u16* __restrict__ img,
    float* __restrict__ bqv, float* __restrict__ bo2) {
  const int NW = 524288;
  const int total = NW + 512 + 256;
  int i = blockIdx.x * blockDim.x + threadIdx.x;
  for (; i < total; i += gridDim.x * blockDim.x) {
    if (i < NW) {
      const int piece = i >> 14, r = i & 16383;
      const int h = piece >> 2, wh = piece & 3;
      float v;
      if (wh < 3) {
        const int n = r >> 8, cpos = (r >> 3) & 31, e = r & 7;
        const int k = ((cpos ^ (n & 7)) << 3) + e;
        const int col = h * 64 + n;
        v = (wh == 0) ? Wq[k * 512 + col] * 0.125f
          : (wh == 1) ? Wk[k * 512 + col] : Wv[k * 512 + col];
      } else {
        const int cc = r >> 6, cpos = (r >> 3) & 7, e = r & 7;
        const int kk = ((cpos ^ (cc & 7)) << 3) + e;
        v = Wo[(h * 64 + kk) * 256 + cc];
      }
      img[i] = f2b(v);
    } else if (i < NW + 512) {
      const int j = i - NW;
      bqv[j] = bq[j] * 0.125f;
    } else {
      const int j = i - NW - 512;
      float acc = bo[j];
      for (int dd = 0; dd < 512; ++dd) acc += bv[dd] * Wo[dd * 256 + j];
      bo2[j] = acc;
    }
  }
}

// ---------------- fully fused axial attention ----------------
// One block per (b,w) column: 512 threads = 8 waves = 4 y-slabs(32) x 2 halves.
// LDS (u16 idx): WB0 0 | WB1 16384 | QB 32768 | KB 40960 | VT 49152 | PB 57344
//   = 144 KiB. xcol (64 KiB) transiently occupies 32768..65536.
// All tile layouts use 16B-chunk ^= (row&7) swizzle -> <=2-way bank conflicts.
// Head loop slots (counted vmcnt(4) keeps next W-piece in flight across barriers):
//   A: stage k  ; q-gemm(WB0)->QB      B: stage v ; k-gemm(WB1)->KB
//   C: stage o  ; v-gemm(WB0)->VT^T    D: QK^T + softmax -> PB (probs, bf16)
//   E: stage q' ; PV(PB,VT)->QB(ab)    F: Oproj accumulate (ab @ WB1)

__global__ __launch_bounds__(512) void fused_axial(
    const float* __restrict__ x, const u16* __restrict__ img,
    const float* __restrict__ bqv, const float* __restrict__ bo2,
    float* __restrict__ out) {
  __shared__ u16 lds[73728];
  const int WB0 = 0, WB1 = 16384, QB = 32768, KB = 40960, VT = 49152, PB = 57344;
  const int XO = 32768;

  const int g = blockIdx.x;
  const int b = g >> 7, w = g & 127;
  const int tid = threadIdx.x, lane = tid & 63, wid = tid >> 6;
  const int s = wid >> 1, nh = wid & 1;
  const int lo = lane & 15, hi = lane >> 4;
  const int l8 = lo & 7;

  // ---- Phase A: x column -> xcol bf16 (swizzled) ----
  {
    const int y = tid >> 2, q4 = tid & 3;
    const float4* xr = (const float4*)(x + ((size_t)((b * 128 + y) * 128 + w)) * 256) + q4 * 16;
#pragma unroll
    for (int c8 = 0; c8 < 8; ++c8) {
      float4 f0 = xr[c8 * 2], f1 = xr[c8 * 2 + 1];
      u16x8 r;
      r[0] = f2b(f0.x); r[1] = f2b(f0.y); r[2] = f2b(f0.z); r[3] = f2b(f0.w);
      r[4] = f2b(f1.x); r[5] = f2b(f1.y); r[6] = f2b(f1.z); r[7] = f2b(f1.w);
      *(u16x8*)&lds[XO + y * 256 + (((q4 * 8 + c8) ^ (y & 7)) << 3)] = r;
    }
  }
  __syncthreads();

  // ---- A-regs: wave's 32-row x-slab (64 VGPR) ----
  bf16x8 areg[2][8];
#pragma unroll
  for (int m = 0; m < 2; ++m)
#pragma unroll
    for (int k8 = 0; k8 < 8; ++k8)
      areg[m][k8] = mfma_ld(&lds[XO + (s * 32 + m * 16 + lo) * 256 + (((k8 * 4 + hi) ^ l8) << 3)]);

  auto stagep = [&](int piece) {
    const u16* src = img + (size_t)piece * 16384;
    u16* dst = &lds[(piece & 1) ? WB1 : WB0];
#pragma unroll
    for (int it = 0; it < 4; ++it)
      gload_lds16(src + (it * 512 + tid) * 8, dst + (it * 512 + tid) * 8);
  };

  stagep(0);  // q_0 -> WB0 (no alias with xcol)
  float bqa = bqv[nh * 32 + lo], bqb = bqv[nh * 32 + 16 + lo];

  f32x4 oacc[2][8];
#pragma unroll
  for (int m = 0; m < 2; ++m)
#pragma unroll
    for (int n = 0; n < 8; ++n) oacc[m][n] = f32x4{0.f, 0.f, 0.f, 0.f};

  LGKM0;  // areg reads complete before qb region is overwritten
  sbar();

  for (int h = 0; h < 8; ++h) {
    const int p0 = h * 4;

    // ---------- slot A: q-gemm (WB0) -> QB ----------
    stagep(p0 + 1);
    VMW(4); sbar();
    {
      f32x4 ga[2][2];
#pragma unroll
      for (int m = 0; m < 2; ++m)
#pragma unroll
        for (int n = 0; n < 2; ++n) ga[m][n] = f32x4{0.f, 0.f, 0.f, 0.f};
#pragma unroll
      for (int k8 = 0; k8 < 8; ++k8) {
        bf16x8 bf0 = mfma_ld(&lds[WB0 + (nh * 32 + lo) * 256 + (((k8 * 4 + hi) ^ l8) << 3)]);
        bf16x8 bf1 = mfma_ld(&lds[WB0 + (nh * 32 + 16 + lo) * 256 + (((k8 * 4 + hi) ^ l8) << 3)]);
#pragma unroll
        for (int m = 0; m < 2; ++m) {
          ga[m][0] = __builtin_amdgcn_mfma_f32_16x16x32_bf16(areg[m][k8], bf0, ga[m][0], 0, 0, 0);
          ga[m][1] = __builtin_amdgcn_mfma_f32_16x16x32_bf16(areg[m][k8], bf1, ga[m][1], 0, 0, 0);
        }
      }
#pragma unroll
      for (int n = 0; n < 2; ++n) {
        const int d = nh * 32 + n * 16 + lo;
        const float bia = n ? bqb : bqa;
#pragma unroll
        for (int m = 0; m < 2; ++m)
#pragma unroll
          for (int j = 0; j < 4; ++j) {
            const int y = s * 32 + m * 16 + hi * 4 + j;
            lds[QB + y * 64 + (((d >> 3) ^ (y & 7)) << 3) + (d & 7)] = f2b(ga[m][n][j] + bia);
          }
      }
    }
    LGKM0; sbar();

    // ---------- slot B: k-gemm (WB1) -> KB ----------
    stagep(p0 + 2);
    VMW(4); sbar();
    {
      f32x4 ga[2][2];
#pragma unroll
      for (int m = 0; m < 2; ++m)
#pragma unroll
        for (int n = 0; n < 2; ++n) ga[m][n] = f32x4{0.f, 0.f, 0.f, 0.f};
#pragma unroll
      for (int k8 = 0; k8 < 8; ++k8) {
        bf16x8 bf0 = mfma_ld(&lds[WB1 + (nh * 32 + lo) * 256 + (((k8 * 4 + hi) ^ l8) << 3)]);
        bf16x8 bf1 = mfma_ld(&lds[WB1 + (nh * 32 + 16 + lo) * 256 + (((k8 * 4 + hi) ^ l8) << 3)]);
#pragma unroll
        for (int m = 0; m < 2; ++m) {
          ga[m][0] = __builtin_amdgcn_mfma_f32_16x16x32_bf16(areg[m][k8], bf0, ga[m][0], 0, 0, 0);
          ga[m][1] = __builtin_amdgcn_mfma_f32_16x16x32_bf16(areg[m][k8], bf1, ga[m][1], 0, 0, 0);
        }
      }
#pragma unroll
      for (int n = 0; n < 2; ++n) {
        const int d = nh * 32 + n * 16 + lo;
#pragma unroll
        for (int m = 0; m < 2; ++m)
#pragma unroll
          for (int j = 0; j < 4; ++j) {
            const int y = s * 32 + m * 16 + hi * 4 + j;
            lds[KB + y * 64 + (((d >> 3) ^ (y & 7)) << 3) + (d & 7)] = f2b(ga[m][n][j]);
          }
      }
    }
    LGKM0; sbar();

    // ---------- slot C: v-gemm (WB0) -> VT (transposed) ----------
    stagep(p0 + 3);
    VMW(4); sbar();
    {
      f32x4 ga[2][2];
#pragma unroll
      for (int m = 0; m < 2; ++m)
#pragma unroll
        for (int n = 0; n < 2; ++n) ga[m][n] = f32x4{0.f, 0.f, 0.f, 0.f};
#pragma unroll
      for (int k8 = 0; k8 < 8; ++k8) {
        bf16x8 bf0 = mfma_ld(&lds[WB0 + (nh * 32 + lo) * 256 + (((k8 * 4 + hi) ^ l8) << 3)]);
        bf16x8 bf1 = mfma_ld(&lds[WB0 + (nh * 32 + 16 + lo) * 256 + (((k8 * 4 + hi) ^ l8) << 3)]);
#pragma unroll
        for (int m = 0; m < 2; ++m) {
          ga[m][0] = __builtin_amdgcn_mfma_f32_16x16x32_bf16(areg[m][k8], bf0, ga[m][0], 0, 0, 0);
          ga[m][1] = __builtin_amdgcn_mfma_f32_16x16x32_bf16(areg[m][k8], bf1, ga[m][1], 0, 0, 0);
        }
      }
      // vt[d][y]: pack 4 consecutive y per lane -> b64 write (bv folded into bo2)
#pragma unroll
      for (int n = 0; n < 2; ++n) {
        const int d = nh * 32 + n * 16 + lo;
#pragma unroll
        for (int m = 0; m < 2; ++m) {
          const int y0 = s * 32 + m * 16 + hi * 4;
          u16x4 pk;
#pragma unroll
          for (int j = 0; j < 4; ++j) pk[j] = f2b(ga[m][n][j]);
          *(u16x4*)&lds[VT + d * 128 + ((((y0 >> 3)) ^ (d & 7)) << 3) + ((hi & 1) * 4)] = pk;
        }
      }
    }
    LGKM0; sbar();

    // ---------- slot D: scores + softmax -> PB (normalized probs) ----------
    {
      f32x4 sacc[8];
#pragma unroll
      for (int n = 0; n < 8; ++n) sacc[n] = f32x4{0.f, 0.f, 0.f, 0.f};
#pragma unroll
      for (int ks = 0; ks < 2; ++ks) {
        bf16x8 aq = mfma_ld(&lds[QB + (wid * 16 + lo) * 64 + (((hi + ks * 4) ^ l8) << 3)]);
#pragma unroll
        for (int n = 0; n < 8; ++n) {
          bf16x8 kf = mfma_ld(&lds[KB + (n * 16 + lo) * 64 + (((hi + ks * 4) ^ l8) << 3)]);
          sacc[n] = __builtin_amdgcn_mfma_f32_16x16x32_bf16(aq, kf, sacc[n], 0, 0, 0);
        }
      }
#pragma unroll
      for (int j = 0; j < 4; ++j) {
        float mx = sacc[0][j];
#pragma unroll
        for (int n = 1; n < 8; ++n) mx = fmaxf(mx, sacc[n][j]);
#pragma unroll
        for (int d = 1; d < 16; d <<= 1) mx = fmaxf(mx, __shfl_xor(mx, d, 64));
        float sum = 0.f;
#pragma unroll
        for (int n = 0; n < 8; ++n) {
          float e = exp2f((sacc[n][j] - mx) * 1.44269504f);
          sacc[n][j] = e;
          sum += e;
        }
#pragma unroll
        for (int d = 1; d < 16; d <<= 1) sum += __shfl_xor(sum, d, 64);
        const float rinv = 1.f / sum;
        const int y = wid * 16 + hi * 4 + j;
#pragma unroll
        for (int n = 0; n < 8; ++n) {
          const int yp = n * 16 + lo;
          lds[PB + y * 128 + ((((yp >> 3)) ^ (y & 7)) << 3) + (yp & 7)] = f2b(sacc[n][j] * rinv);
        }
      }
    }
    LGKM0; sbar();

    // ---------- slot E: PV -> QB (attout), prefetch q_{h+1} ----------
    if (h < 7) {
      stagep(p0 + 4);
      bqa = bqv[(h + 1) * 64 + nh * 32 + lo];
      bqb = bqv[(h + 1) * 64 + nh * 32 + 16 + lo];
    }
    {
      f32x4 pv[2][2];
#pragma unroll
      for (int m = 0; m < 2; ++m)
#pragma unroll
        for (int n = 0; n < 2; ++n) pv[m][n] = f32x4{0.f, 0.f, 0.f, 0.f};
#pragma unroll
      for (int ks = 0; ks < 4; ++ks) {
        bf16x8 ap[2];
#pragma unroll
        for (int m = 0; m < 2; ++m)
          ap[m] = mfma_ld(&lds[PB + (s * 32 + m * 16 + lo) * 128 + (((hi + ks * 4) ^ l8) << 3)]);
#pragma unroll
        for (int n = 0; n < 2; ++n) {
          const int d = nh * 32 + n * 16 + lo;
          bf16x8 vf = mfma_ld(&lds[VT + d * 128 + (((hi + ks * 4) ^ l8) << 3)]);
#pragma unroll
          for (int m = 0; m < 2; ++m)
            pv[m][n] = __builtin_amdgcn_mfma_f32_16x16x32_bf16(ap[m], vf, pv[m][n], 0, 0, 0);
        }
      }
#pragma unroll
      for (int n = 0; n < 2; ++n) {
        const int d = nh * 32 + n * 16 + lo;
#pragma unroll
        for (int m = 0; m < 2; ++m)
#pragma unroll
          for (int j = 0; j < 4; ++j) {
            const int y = s * 32 + m * 16 + hi * 4 + j;
            lds[QB + y * 64 + (((d >> 3) ^ (y & 7)) << 3) + (d & 7)] = f2b(pv[m][n][j]);
          }
      }
    }
    if (h < 7) { VMW(4); } else { VMW(0); }
    LGKM0; sbar();

    // ---------- slot F: out += attout_h @ Wo_h (WB1) ----------
    {
#pragma unroll
      for (int ks = 0; ks < 2; ++ks) {
        bf16x8 af0 = mfma_ld(&lds[QB + (s * 32 + lo) * 64 + (((hi + ks * 4) ^ l8) << 3)]);
        bf16x8 af1 = mfma_ld(&lds[QB + (s * 32 + 16 + lo) * 64 + (((hi + ks * 4) ^ l8) << 3)]);
#pragma unroll
        for (int n = 0; n < 8; ++n) {
          const int c = nh * 128 + n * 16 + lo;
          bf16x8 wf = mfma_ld(&lds[WB1 + c * 64 + (((hi + ks * 4) ^ l8) << 3)]);
          oacc[0][n] = __builtin_amdgcn_mfma_f32_16x16x32_bf16(af0, wf, oacc[0][n], 0, 0, 0);
          oacc[1][n] = __builtin_amdgcn_mfma_f32_16x16x32_bf16(af1, wf, oacc[1][n], 0, 0, 0);
        }
      }
    }
    LGKM0; sbar();
  }

  // ---- epilogue: bias + fp32 store ----
  float bbn[8];
#pragma unroll
  for (int n = 0; n < 8; ++n) bbn[n] = bo2[nh * 128 + n * 16 + lo];
#pragma unroll
  for (int m = 0; m < 2; ++m)
#pragma unroll
    for (int j = 0; j < 4; ++j) {
      const int y = s * 32 + m * 16 + hi * 4 + j;
      float* orow = out + ((size_t)((b * 128 + y) * 128 + w)) * 256 + nh * 128;
#pragma unroll
      for (int n = 0; n < 8; ++n) orow[n * 16 + lo] = oacc[m][n][j] + bbn[n];
    }
}

// ---------------- launch ----------------
// ws: img [0, 1 MiB) | bqv [1 MiB, +2 KiB) | bo2 (+1 KiB)

extern "C" void kernel_launch(void* const* d_in, const int* in_sizes, int n_in,
                              void* d_out, int out_size, void* d_ws, size_t ws_size,
                              hipStream_t stream) {
  (void)in_sizes; (void)n_in; (void)out_size; (void)ws_size;
  const float* x  = (const float*)d_in[0];
  const float* Wq = (const float*)d_in[1];
  const float* bq = (const float*)d_in[2];
  const float* Wk = (const float*)d_in[3];
  const float* Wv = (const float*)d_in[5];
  const float* bv = (const float*)d_in[6];
  const float* Wo = (const float*)d_in[7];
  const float* bo = (const float*)d_in[8];
  float* out = (float*)d_out;

  char* ws = (char*)d_ws;
  const size_t MiB = (size_t)1 << 20;
  u16* img   = (u16*)ws;
  float* bqv = (float*)(ws + MiB);
  float* bo2 = bqv + 512;

  prep_w2<<<512, 256, 0, stream>>>(Wq, Wk, Wv, Wo, bq, bv, bo, img, bqv, bo2);
  fused_axial<<<512, 512, 0, stream>>>(x, img, bqv, bo2, out);
}

// Round 3
// 225.852 us; speedup vs baseline: 1.4319x; 1.4319x over previous
//
#include <hip/hip_runtime.h>

typedef unsigned short u16;
typedef __attribute__((ext_vector_type(8))) short bf16x8;
typedef __attribute__((ext_vector_type(8))) unsigned short u16x8;
typedef __attribute__((ext_vector_type(4))) float f32x4;

#define DEVI static __device__ __forceinline__

DEVI u16 f2b(float f) {
  unsigned u = __builtin_bit_cast(unsigned, f);
  return (u16)((u + 0x7FFFu + ((u >> 16) & 1u)) >> 16);
}

DEVI void gload_lds16(const void* g, void* l) {
  __builtin_amdgcn_global_load_lds(
      (const __attribute__((address_space(1))) unsigned int*)g,
      (__attribute__((address_space(3))) unsigned int*)l, 16, 0, 0);
}

// ---------------- prep kernels ----------------

__global__ __launch_bounds__(256) void prep_x(const float* __restrict__ x, u16* __restrict__ xb) {
  const int n8 = 65536 * 256 / 8;
  int i = blockIdx.x * blockDim.x + threadIdx.x;
  for (; i < n8; i += gridDim.x * blockDim.x) {
    const float4* p = (const float4*)x + (size_t)i * 2;
    float4 a = p[0], b = p[1];
    u16x8 r;
    r[0] = f2b(a.x); r[1] = f2b(a.y); r[2] = f2b(a.z); r[3] = f2b(a.w);
    r[4] = f2b(b.x); r[5] = f2b(b.y); r[6] = f2b(b.z); r[7] = f2b(b.w);
    *(u16x8*)(xb + (size_t)i * 8) = r;
  }
}

// wqkvT[1536][256]: row n<512 -> Wq[:,n]*0.125 ; 512..1023 -> Wk ; 1024.. -> Wv
// woT[256][512]: row n -> Wo[:,n] ;  bqkv[1536] = concat(bq*0.125, bk, bv)
__global__ __launch_bounds__(256) void prep_w(
    const float* __restrict__ Wq, const float* __restrict__ Wk,
    const float* __restrict__ Wv, const float* __restrict__ Wo,
    const float* __restrict__ bq, const float* __restrict__ bk, const float* __restrict__ bv,
    u16* __restrict__ wqkvT, u16* __restrict__ woT, float* __restrict__ bqkv) {
  const int NW1 = 1536 * 256, NW2 = 256 * 512;
  const int total = NW1 + NW2 + 1536;
  int i = blockIdx.x * blockDim.x + threadIdx.x;
  for (; i < total; i += gridDim.x * blockDim.x) {
    if (i < NW1) {
      int nn = i >> 8, kk = i & 255;
      float v;
      if (nn < 512)       v = Wq[kk * 512 + nn] * 0.125f;
      else if (nn < 1024) v = Wk[kk * 512 + (nn - 512)];
      else                v = Wv[kk * 512 + (nn - 1024)];
      wqkvT[i] = f2b(v);
    } else if (i < NW1 + NW2) {
      int j = i - NW1;
      int nn = j >> 9, kk = j & 511;
      woT[j] = f2b(Wo[kk * 256 + nn]);
    } else {
      int j = i - NW1 - NW2;
      bqkv[j] = (j < 512) ? bq[j] * 0.125f : (j < 1024 ? bk[j - 512] : bv[j - 1024]);
    }
  }
}

// ---------------- GEMM: C[M,N] = A[M,K](bf16) * Bt[N,K]^T(bf16) + bias ----------------
// 256x256 tile, BK=64, 16 waves (4M x 4N, each 64x64 out) @ 1024 threads.
// Double-buffered (128 KiB LDS) with COUNTED vmcnt; raw s_barrier; LDS chunk-XOR swizzle
// applied via pre-swizzled GLOBAL source (rule #21); XCD-bijective block swizzle.

template <int KK, bool OUT_BF16>
__global__ __launch_bounds__(1024) void gemm256(
    const u16* __restrict__ A, const u16* __restrict__ Bt,
    const float* __restrict__ bias, void* __restrict__ Cv, int N) {
  constexpr int NT = KK / 64;
  __shared__ u16 smem[65536];  // 2 x [A 256x64 | B 256x64] bf16 = 128 KiB
  const int tid = threadIdx.x;
  const int lane = tid & 63, wid = tid >> 6;   // wid 0..15
  const int nTn = N >> 8;
  const int qx = gridDim.x >> 3;
  const int wg = (blockIdx.x & 7) * qx + (blockIdx.x >> 3);
  const long m0 = (long)(wg / nTn) * 256;
  const long n0 = (long)(wg % nTn) * 256;
  const int wr = wid >> 2, wc = wid & 3;       // 4x4 waves, each 64x64 out
  const int hi = lane >> 4, lo = lane & 15;
  const u16* Ab = A + m0 * KK;
  const u16* Bb = Bt + n0 * KK;
  const int srow_ = tid >> 3;  // 0..127: row within a 128-row staging round
  const int schunk = tid & 7;  // 16B chunk within row

  f32x4 acc[4][4];
#pragma unroll
  for (int mi = 0; mi < 4; ++mi)
#pragma unroll
    for (int ni = 0; ni < 4; ++ni) acc[mi][ni] = f32x4{0.f, 0.f, 0.f, 0.f};

  auto stage = [&](int t) {
    u16* base = &smem[(t & 1) * 32768];
    const int kt = t * 64;
#pragma unroll
    for (int j = 0; j < 2; ++j) {
      int row = j * 128 + srow_;
      int colE = (schunk ^ (row & 7)) << 3;  // inverse-swizzled global source
      gload_lds16(Ab + (long)row * KK + kt + colE, &base[(j * 1024 + tid) * 8]);
    }
#pragma unroll
    for (int j = 0; j < 2; ++j) {
      int row = j * 128 + srow_;
      int colE = (schunk ^ (row & 7)) << 3;
      gload_lds16(Bb + (long)row * KK + kt + colE, &base[16384 + (j * 1024 + tid) * 8]);
    }
  };

  stage(0);
#pragma unroll
  for (int t = 0; t < NT; ++t) {
    if (t + 1 < NT) {
      stage(t + 1);
      asm volatile("s_waitcnt vmcnt(4)" ::: "memory");  // batch t done; batch t+1 in flight
    } else {
      asm volatile("s_waitcnt vmcnt(0)" ::: "memory");
    }
    __builtin_amdgcn_sched_barrier(0);
    __builtin_amdgcn_s_barrier();
    const u16* aB = &smem[(t & 1) * 32768];
    const u16* bB = aB + 16384;
#pragma unroll
    for (int ks = 0; ks < 2; ++ks) {
      const int slot = ((hi + ks * 4) ^ (lo & 7)) << 3;  // swizzled k-chunk
      bf16x8 af[4], bfr[4];
#pragma unroll
      for (int mi = 0; mi < 4; ++mi)
        af[mi] = *(const bf16x8*)&aB[(wr * 64 + mi * 16 + lo) * 64 + slot];
#pragma unroll
      for (int ni = 0; ni < 4; ++ni)
        bfr[ni] = *(const bf16x8*)&bB[(wc * 64 + ni * 16 + lo) * 64 + slot];
#pragma unroll
      for (int mi = 0; mi < 4; ++mi)
#pragma unroll
        for (int ni = 0; ni < 4; ++ni)
          acc[mi][ni] = __builtin_amdgcn_mfma_f32_16x16x32_bf16(af[mi], bfr[ni], acc[mi][ni], 0, 0, 0);
    }
    __builtin_amdgcn_sched_barrier(0);
    __builtin_amdgcn_s_barrier();
  }

  float bb[4];
#pragma unroll
  for (int ni = 0; ni < 4; ++ni) bb[ni] = bias[n0 + wc * 64 + ni * 16 + lo];

  if (OUT_BF16) {
    // single-pass epilogue: full 256x256 bf16 tile = exactly 128 KiB smem.
    u16* Cg = (u16*)Cv;
#pragma unroll
    for (int mi = 0; mi < 4; ++mi)
#pragma unroll
      for (int ni = 0; ni < 4; ++ni) {
#pragma unroll
        for (int j = 0; j < 4; ++j) {
          int row = wr * 64 + mi * 16 + hi * 4 + j;
          int chunk = (wc * 8 + ni * 2 + (lo >> 3)) ^ ((row >> 2) & 7);
          smem[row * 256 + chunk * 8 + (lo & 7)] = f2b(acc[mi][ni][j] + bb[ni]);
        }
      }
    __syncthreads();
#pragma unroll
    for (int it = 0; it < 8; ++it) {
      int idx = it * 1024 + tid;
      int row = idx >> 5, c = idx & 31;
      int cs = c ^ ((row >> 2) & 7);
      *(u16x8*)(Cg + (m0 + row) * N + n0 + c * 8) = *(const u16x8*)&smem[row * 256 + cs * 8];
    }
  } else {
    float* Cg = (float*)Cv;
#pragma unroll
    for (int mi = 0; mi < 4; ++mi)
#pragma unroll
      for (int ni = 0; ni < 4; ++ni) {
        long cg = n0 + wc * 64 + ni * 16 + lo;
#pragma unroll
        for (int j = 0; j < 4; ++j)
          Cg[(m0 + wr * 64 + mi * 16 + hi * 4 + j) * N + cg] = acc[mi][ni][j] + bb[ni];
      }
  }
}

// ---------------- axial attention v2 ----------------
// one block (4 waves) per (b,w,head); token row = (b*128+y)*128 + w.
// Changes vs v1: Q straight to registers (no LDS); K reg-staged then ds_write
// with chunk^(row&7) swizzle; vt/pld writes AND all fragment reads swizzled
// (kills the 16-way conflicts on 128/256-B-stride rows); setprio around MFMA.
// LDS 48 KB: kld [0,16K) | vt [32K,48K) ; pld [0,32K) aliases kld after QK^T.

__global__ __launch_bounds__(256) void attn_axial(const u16* __restrict__ qkv,
                                                  u16* __restrict__ ao) {
  __shared__ u16 smem[24576];
  u16* kld = smem;               // [128][64]  swizzled chunks
  u16* pld = smem;               // [128][128] swizzled (after QK^T)
  u16* vt  = smem + 16384;       // [64][128]  swizzled (vt[dh][y])

  const int g = blockIdx.x;
  const int n = g & 7, w = (g >> 3) & 127, b = g >> 10;
  const int tid = threadIdx.x, lane = tid & 63, wid = tid >> 6;
  const size_t ystr = (size_t)128 * 1536;
  const size_t base = (size_t)(b * 16384 + w) * 1536;
  const size_t bq_ = base + n * 64;
  const size_t bk_ = base + 512 + n * 64;
  const size_t bv_ = base + 1024 + n * 64;
  const int hi = lane >> 4, lo = lane & 15;

  // ---- K: global -> regs ----
  u16x8 kreg[4];
  const int kr0 = tid >> 3, kc = tid & 7;
#pragma unroll
  for (int i = 0; i < 4; ++i)
    kreg[i] = *(const u16x8*)(qkv + bk_ + (size_t)(i * 32 + kr0) * ystr + kc * 8);

  // ---- V: global -> regs (2 rows x 16 dh per thread) ----
  u16x8 va0, va1, vc0, vc1;
  const int vh2 = tid >> 6, vyp = (tid & 63) * 2;
  {
    const u16* g0 = qkv + bv_ + (size_t)vyp * ystr + vh2 * 16;
    va0 = *(const u16x8*)g0;
    va1 = *(const u16x8*)(g0 + 8);
    vc0 = *(const u16x8*)(g0 + ystr);
    vc1 = *(const u16x8*)(g0 + ystr + 8);
  }

  // ---- Q: global -> registers (MFMA A-fragments directly) ----
  bf16x8 aq[2][2];  // [mi][ks]
#pragma unroll
  for (int mi = 0; mi < 2; ++mi)
#pragma unroll
    for (int ks = 0; ks < 2; ++ks)
      aq[mi][ks] = *(const bf16x8*)(qkv + bq_ +
          (size_t)(wid * 32 + mi * 16 + lo) * ystr + hi * 8 + ks * 32);

  // ---- swizzled LDS writes ----
#pragma unroll
  for (int i = 0; i < 4; ++i) {
    const int r = i * 32 + kr0;
    *(u16x8*)&kld[r * 64 + ((kc ^ (r & 7)) << 3)] = kreg[i];
  }
  {
    unsigned* vt32 = (unsigned*)vt;
    const int cch = vyp >> 3;          // 16B chunk 0..15
    const int cw = (vyp >> 1) & 3;     // dword within chunk
#pragma unroll
    for (int e = 0; e < 8; ++e) {
      const int d0 = vh2 * 16 + e, d1 = vh2 * 16 + 8 + e;
      const int c0s = (cch & 8) | ((cch & 7) ^ (d0 & 7));
      const int c1s = (cch & 8) | ((cch & 7) ^ (d1 & 7));
      vt32[d0 * 64 + c0s * 4 + cw] = (unsigned)va0[e] | ((unsigned)vc0[e] << 16);
      vt32[d1 * 64 + c1s * 4 + cw] = (unsigned)va1[e] | ((unsigned)vc1[e] << 16);
    }
  }
  __syncthreads();

  // ---- QK^T ----
  f32x4 s[2][8];
#pragma unroll
  for (int mi = 0; mi < 2; ++mi)
#pragma unroll
    for (int ni = 0; ni < 8; ++ni) s[mi][ni] = f32x4{0.f, 0.f, 0.f, 0.f};
  __builtin_amdgcn_s_setprio(1);
#pragma unroll
  for (int ks = 0; ks < 2; ++ks) {
#pragma unroll
    for (int ni = 0; ni < 8; ++ni) {
      const int kr = ni * 16 + lo;
      bf16x8 kf = *(const bf16x8*)&kld[kr * 64 + (((hi + ks * 4) ^ (kr & 7)) << 3)];
#pragma unroll
      for (int mi = 0; mi < 2; ++mi)
        s[mi][ni] = __builtin_amdgcn_mfma_f32_16x16x32_bf16(aq[mi][ks], kf, s[mi][ni], 0, 0, 0);
    }
  }
  __builtin_amdgcn_s_setprio(0);
  __syncthreads();  // kld dead; pld may overwrite

  // ---- softmax (unnormalized P in LDS; 1/sum applied at the end) ----
  float rinv[2][4];
#pragma unroll
  for (int mi = 0; mi < 2; ++mi) {
#pragma unroll
    for (int j = 0; j < 4; ++j) {
      float m = s[mi][0][j];
#pragma unroll
      for (int ni = 1; ni < 8; ++ni) m = fmaxf(m, s[mi][ni][j]);
#pragma unroll
      for (int d = 1; d < 16; d <<= 1) m = fmaxf(m, __shfl_xor(m, d, 64));
      float sum = 0.f;
#pragma unroll
      for (int ni = 0; ni < 8; ++ni) {
        float e = exp2f((s[mi][ni][j] - m) * 1.44269504f);
        s[mi][ni][j] = e;
        sum += e;
      }
#pragma unroll
      for (int d = 1; d < 16; d <<= 1) sum += __shfl_xor(sum, d, 64);
      rinv[mi][j] = 1.f / sum;
      const int q = wid * 32 + mi * 16 + hi * 4 + j;
#pragma unroll
      for (int ni = 0; ni < 8; ++ni) {
        const int yp = ni * 16 + lo;
        const int cch = yp >> 3;
        const int cs = (cch & 8) | ((cch & 7) ^ (q & 7));
        pld[q * 128 + cs * 8 + (yp & 7)] = f2b(s[mi][ni][j]);
      }
    }
  }

  // ---- PV (per-wave P slab; no cross-wave dependency -> no barrier) ----
  f32x4 o[2][4];
#pragma unroll
  for (int mi = 0; mi < 2; ++mi)
#pragma unroll
    for (int ni = 0; ni < 4; ++ni) o[mi][ni] = f32x4{0.f, 0.f, 0.f, 0.f};
  __builtin_amdgcn_s_setprio(1);
#pragma unroll
  for (int ks = 0; ks < 4; ++ks) {
    const int cch = hi + ks * 4;
    bf16x8 ap[2];
#pragma unroll
    for (int mi = 0; mi < 2; ++mi) {
      const int pr = wid * 32 + mi * 16 + lo;
      const int cs = (cch & 8) | ((cch & 7) ^ (pr & 7));
      ap[mi] = *(const bf16x8*)&pld[pr * 128 + cs * 8];
    }
#pragma unroll
    for (int ni = 0; ni < 4; ++ni) {
      const int vr = ni * 16 + lo;
      const int cs = (cch & 8) | ((cch & 7) ^ (vr & 7));
      bf16x8 vf = *(const bf16x8*)&vt[vr * 128 + cs * 8];
#pragma unroll
      for (int mi = 0; mi < 2; ++mi)
        o[mi][ni] = __builtin_amdgcn_mfma_f32_16x16x32_bf16(ap[mi], vf, o[mi][ni], 0, 0, 0);
    }
  }
  __builtin_amdgcn_s_setprio(0);

#pragma unroll
  for (int mi = 0; mi < 2; ++mi)
#pragma unroll
    for (int j = 0; j < 4; ++j) {
      const int q = wid * 32 + mi * 16 + hi * 4 + j;
      const size_t obase = ((size_t)(b * 16384 + q * 128 + w)) * 512 + (size_t)n * 64;
#pragma unroll
      for (int ni = 0; ni < 4; ++ni)
        ao[obase + ni * 16 + lo] = f2b(o[mi][ni][j] * rinv[mi][j]);
    }
}

// ---------------- launch ----------------
// ws: qkv [0,192MiB) | xb [192,224) | weights [224,~226)
// ao (bf16, 64 MB) lives IN d_out; gemm2 runs in-place (each block reads only its
// own 256 rows as bf16 before overwriting them as f32 -> race-free, deterministic).

extern "C" void kernel_launch(void* const* d_in, const int* in_sizes, int n_in,
                              void* d_out, int out_size, void* d_ws, size_t ws_size,
                              hipStream_t stream) {
  (void)in_sizes; (void)n_in; (void)out_size; (void)ws_size;
  const float* x  = (const float*)d_in[0];
  const float* Wq = (const float*)d_in[1];
  const float* bq = (const float*)d_in[2];
  const float* Wk = (const float*)d_in[3];
  const float* bk = (const float*)d_in[4];
  const float* Wv = (const float*)d_in[5];
  const float* bv = (const float*)d_in[6];
  const float* Wo = (const float*)d_in[7];
  const float* bo = (const float*)d_in[8];
  float* out = (float*)d_out;

  char* ws = (char*)d_ws;
  const size_t MiB = (size_t)1 << 20;
  u16* qkv   = (u16*)ws;
  u16* xb    = (u16*)(ws + 192 * MiB);
  u16* wqkvT = (u16*)(ws + 224 * MiB);
  u16* woT   = wqkvT + 1536 * 256;
  float* bqkv = (float*)(woT + 256 * 512);

  prep_x<<<2048, 256, 0, stream>>>(x, xb);
  prep_w<<<512, 256, 0, stream>>>(Wq, Wk, Wv, Wo, bq, bk, bv, wqkvT, woT, bqkv);

  gemm256<256, true><<<1536, 1024, 0, stream>>>(xb, wqkvT, bqkv, qkv, 1536);
  attn_axial<<<4096, 256, 0, stream>>>(qkv, (u16*)out);
  gemm256<512, false><<<256, 1024, 0, stream>>>((const u16*)out, woT, bo, out, 256);
}